// Round 4
// baseline (643.109 us; speedup 1.0000x reference)
//
#include <hip/hip_runtime.h>

#define OUTHALF 8388608
#define WSTR    578     // wt row stride (dwords): even (b64-aligned), %32==2 -> <=2-way banks

// grid=512, block=256. Block owns NT=64 n and all K=1024.
// 2 k-passes of 512; 16 c-chunks of 16 per pass (32 phases).
// Micro-tile 8n x 16k: ng = t>>5 (8 groups), kg = t&31 (32 groups of 16 k).
// T14 staging: phase p+1's global loads issued into regs before phase p's compute.
__global__ __launch_bounds__(256, 2) void vq_kernel(
    const float* __restrict__ z,    // [32,256,32,32]
    const float* __restrict__ w,    // [1024,256]
    float* __restrict__ out)        // code(8388608) | detached(8388608) | idx(32768) as float
{
    __shared__ float wt[16][WSTR];  // 36992 B
    __shared__ float zt[16][64];    //  4096 B
    __shared__ float w2s[1024];     //  4096 B
    __shared__ int   idxb[64];      //   256 B

    const int t = threadIdx.x;

    const int n0  = blockIdx.x * 64;
    const int b   = n0 >> 10;
    const int hw0 = n0 & 1023;
    const float* zb = z + (size_t)b * (256 * 1024) + hw0;

    // ---- prefetch phase 0 into regs (kt=0, ct=0)
    float4 wreg[8];
    float4 zreg;
    #pragma unroll
    for (int r = 0; r < 8; ++r)
        wreg[r] = *reinterpret_cast<const float4*>(
            w + (size_t)(r * 64 + (t >> 2)) * 256 + (t & 3) * 4);
    zreg = *reinterpret_cast<const float4*>(zb + (size_t)(t >> 4) * 1024 + (t & 15) * 4);

    // ---- ||w_k||^2, sequential over c (identical rounding chain to passing rounds)
    for (int kk = t; kk < 1024; kk += 256) {
        const float4* row = reinterpret_cast<const float4*>(w + (size_t)kk * 256);
        float s = 0.0f;
        #pragma unroll 4
        for (int c4 = 0; c4 < 64; ++c4) {
            float4 v = row[c4];
            s += v.x * v.x;
            s += v.y * v.y;
            s += v.z * v.z;
            s += v.w * v.w;
        }
        w2s[kk] = s;
    }

    const int ng = t >> 5;
    const int kg = t & 31;

    float rmin[8], z2v[8];
    int   ridx[8];
    #pragma unroll
    for (int i = 0; i < 8; ++i) { rmin[i] = 3.4e38f; ridx[i] = 0; z2v[i] = 0.0f; }

    for (int kt = 0; kt < 2; ++kt) {
        float acc[8][16];
        #pragma unroll
        for (int i = 0; i < 8; ++i)
            #pragma unroll
            for (int j = 0; j < 16; ++j) acc[i][j] = 0.0f;

        for (int ct = 0; ct < 16; ++ct) {
            __syncthreads();   // previous compute done reading LDS
            // write staged regs -> LDS (w transposed into k-groups of 16 + 2 pad)
            #pragma unroll
            for (int r = 0; r < 8; ++r) {
                int kloc = r * 64 + (t >> 2);
                int goff = (kloc >> 4) * 18 + (kloc & 15);
                int crow = (t & 3) * 4;
                wt[crow + 0][goff] = wreg[r].x;
                wt[crow + 1][goff] = wreg[r].y;
                wt[crow + 2][goff] = wreg[r].z;
                wt[crow + 3][goff] = wreg[r].w;
            }
            *reinterpret_cast<float4*>(&zt[t >> 4][(t & 15) * 4]) = zreg;
            __syncthreads();

            // issue next phase's global loads (latency hides under compute below)
            int pn = kt * 16 + ct + 1;
            if (pn < 32) {
                int kt2 = pn >> 4, ct2 = pn & 15;
                #pragma unroll
                for (int r = 0; r < 8; ++r)
                    wreg[r] = *reinterpret_cast<const float4*>(
                        w + (size_t)(kt2 * 512 + r * 64 + (t >> 2)) * 256 + ct2 * 16 + (t & 3) * 4);
                zreg = *reinterpret_cast<const float4*>(
                    zb + (size_t)(ct2 * 16 + (t >> 4)) * 1024 + (t & 15) * 4);
            }

            // compute: 16 c-iters, 8n x 16k FMAs each
            const float* ztp = &zt[0][ng * 8];
            const float* wtp = &wt[0][kg * 18];
            if (kt == 0) {
                #pragma unroll 4
                for (int c = 0; c < 16; ++c) {
                    const float* zp = ztp + c * 64;
                    const float* wp = wtp + c * WSTR;
                    float4 za = *reinterpret_cast<const float4*>(zp);
                    float4 zc = *reinterpret_cast<const float4*>(zp + 4);
                    float zr[8] = {za.x, za.y, za.z, za.w, zc.x, zc.y, zc.z, zc.w};
                    float wr[16];
                    #pragma unroll
                    for (int q = 0; q < 8; ++q) {
                        float2 wv = *reinterpret_cast<const float2*>(wp + 2 * q);
                        wr[2 * q] = wv.x; wr[2 * q + 1] = wv.y;
                    }
                    #pragma unroll
                    for (int i = 0; i < 8; ++i) {
                        #pragma unroll
                        for (int j = 0; j < 16; ++j) acc[i][j] += zr[i] * wr[j];
                        z2v[i] += zr[i] * zr[i];
                    }
                }
            } else {
                #pragma unroll 4
                for (int c = 0; c < 16; ++c) {
                    const float* zp = ztp + c * 64;
                    const float* wp = wtp + c * WSTR;
                    float4 za = *reinterpret_cast<const float4*>(zp);
                    float4 zc = *reinterpret_cast<const float4*>(zp + 4);
                    float zr[8] = {za.x, za.y, za.z, za.w, zc.x, zc.y, zc.z, zc.w};
                    float wr[16];
                    #pragma unroll
                    for (int q = 0; q < 8; ++q) {
                        float2 wv = *reinterpret_cast<const float2*>(wp + 2 * q);
                        wr[2 * q] = wv.x; wr[2 * q + 1] = wv.y;
                    }
                    #pragma unroll
                    for (int i = 0; i < 8; ++i)
                        #pragma unroll
                        for (int j = 0; j < 16; ++j) acc[i][j] += zr[i] * wr[j];
                }
            }
        }

        // finalize pass: dist = fl(fl(z2 - 2*dot) + w2); per-thread k ascending over (kt, j)
        #pragma unroll
        for (int j = 0; j < 16; ++j) {
            int kk = kt * 512 + kg * 16 + j;
            float w2v = w2s[kk];
            #pragma unroll
            for (int i = 0; i < 8; ++i) {
                float d = (z2v[i] - 2.0f * acc[i][j]) + w2v;
                if (d < rmin[i]) { rmin[i] = d; ridx[i] = kk; }
            }
        }
    }

    // ---- argmin reduce across kg lanes (xor 1..16), index tie-break
    #pragma unroll
    for (int m = 1; m <= 16; m <<= 1) {
        #pragma unroll
        for (int i = 0; i < 8; ++i) {
            float vo = __shfl_xor(rmin[i], m, 64);
            int   io = __shfl_xor(ridx[i], m, 64);
            if (vo < rmin[i] || (vo == rmin[i] && io < ridx[i])) { rmin[i] = vo; ridx[i] = io; }
        }
    }
    if (kg == 0) {
        #pragma unroll
        for (int i = 0; i < 8; ++i) {
            idxb[ng * 8 + i] = ridx[i];
            out[(size_t)2 * OUTHALF + n0 + ng * 8 + i] = (float)ridx[i];
        }
    }

    // ---- gather + transpose epilogue (gbuf aliases wt)
    float (*gbuf)[68] = reinterpret_cast<float (*)[68]>(&wt[0][0]);
    float* out0 = out;
    float* out1 = out + OUTHALF;
    const size_t obase = (size_t)b * (256 * 1024) + hw0;

    for (int ct = 0; ct < 4; ++ct) {
        __syncthreads();
        {
            int n = t & 63, seg = t >> 6;
            int kk = idxb[n];
            #pragma unroll
            for (int u = 0; u < 4; ++u) {
                int c = seg * 16 + u * 4;
                float4 v = *reinterpret_cast<const float4*>(
                    w + (size_t)kk * 256 + ct * 64 + c);
                gbuf[c + 0][n] = v.x;
                gbuf[c + 1][n] = v.y;
                gbuf[c + 2][n] = v.z;
                gbuf[c + 3][n] = v.w;
            }
        }
        __syncthreads();
        #pragma unroll
        for (int p = 0; p < 16; ++p) {
            int c = p * 4 + (t >> 6);
            int n = t & 63;
            float cv = gbuf[c][n];
            size_t off = (size_t)(ct * 64 + c) * 1024 + n;
            float zz = zb[off];
            out0[obase + off] = cv;
            out1[obase + off] = (cv - zz) + zz;   // replicate reference rounding chain
        }
    }
}

extern "C" void kernel_launch(void* const* d_in, const int* in_sizes, int n_in,
                              void* d_out, int out_size, void* d_ws, size_t ws_size,
                              hipStream_t stream) {
    const float* z = (const float*)d_in[0];
    const float* w = (const float*)d_in[1];
    float* out = (float*)d_out;
    vq_kernel<<<512, 256, 0, stream>>>(z, w, out);
}

// Round 5
// 413.767 us; speedup vs baseline: 1.5543x; 1.5543x over previous
//
#include <hip/hip_runtime.h>

#define OUTHALF 8388608

// Round-5 design:
//   grid = 1024 blocks x 256 threads. Block owns 32 n (one b, contiguous hw), all K=1024.
//   Lane k-column: k_local = t (4 waves x 64 = 256 k per pass), 4 kt passes cover K.
//   Per c-iter: 32 FMAs (acc[32] over n), w operand = 1 float from regs (preloaded from
//   LDS k-row), z operands = 32 floats in SGPRs via s_load_dwordx16 x2 (ping-pong).
//   Inner loop is DS-free so lgkmcnt waits only count SMEM -> 1-c lookahead works.
//   Numeric chains identical to passing rounds 1/3 (sequential-c fma; fl(fl(z2-2dot)+w2);
//   first-index argmin via strict-< + u64 (distbits<<32|k) min-reduce; (c-z)+z epilogue).

typedef float sf16 __attribute__((ext_vector_type(16)));

#define Z_ISSUE(A0, A1, P) \
  asm volatile("s_load_dwordx16 %0, %2, 0\n\ts_load_dwordx16 %1, %2, 0x40" \
               : "=s"(A0), "=s"(A1) : "s"(P))

#define Z_WAIT(A0, A1, ANCH) \
  asm volatile("s_waitcnt lgkmcnt(0)" : "+s"(A0), "+s"(A1), "+v"(ANCH))

__global__ __launch_bounds__(256) void vq_kernel(
    const float* __restrict__ z,    // [32,256,32,32]
    const float* __restrict__ w,    // [1024,256]
    float* __restrict__ out)        // code(8388608) | detached(8388608) | idx(32768) as float
{
    __shared__ float wt[256 * 36];                 // w chunk, [k_local][c 0..31], stride 36
    __shared__ unsigned long long wred[4][32];
    __shared__ float z2s[32];
    __shared__ int   idxb[32];

    const int t   = threadIdx.x;
    const int n0  = blockIdx.x * 32;
    const int b   = n0 >> 10;
    const int hw0 = n0 & 1023;
    const float* zcol = z + (size_t)b * 262144 + hw0;

    // ---- z2 for the block's 32 n (sequential-c fma chain, as in passing rounds)
    if (t < 32) {
        const float* p = zcol + t;
        float s = 0.0f;
        #pragma unroll 8
        for (int c = 0; c < 256; ++c) {
            float v = p[(size_t)c * 1024];
            s = fmaf(v, v, s);
        }
        z2s[t] = s;
    }

    const int lane = t & 63;
    const int wv   = t >> 6;

    float rmin[32];
    unsigned tag0 = 0u, tag1 = 0u;                 // 2-bit kt tag per n
    #pragma unroll
    for (int n = 0; n < 32; ++n) rmin[n] = 3.4e38f;

    sf16 zA0, zA1, zB0, zB1;
    Z_ISSUE(zA0, zA1, zcol);                       // cg = 0
    {
        float dummy = 0.0f;
        Z_WAIT(zA0, zA1, dummy);
    }

    #pragma unroll 1
    for (int kt = 0; kt < 4; ++kt) {
        float acc[32];
        #pragma unroll
        for (int n = 0; n < 32; ++n) acc[n] = 0.0f;
        float w2a = 0.0f;

        #pragma unroll 1
        for (int ct = 0; ct < 8; ++ct) {
            __syncthreads();
            // stage w chunk: k_local 0..255 (global kt*256+k), c 0..31 (global ct*32+c)
            {
                const int kk = t >> 3;
                const int c4 = (t & 7) * 4;
                const float* wp = w + (size_t)(kt * 256 + kk) * 256 + ct * 32 + c4;
                #pragma unroll
                for (int r = 0; r < 8; ++r) {
                    float4 v = *reinterpret_cast<const float4*>(wp + (size_t)r * 32 * 256);
                    *reinterpret_cast<float4*>(&wt[(kk + r * 32) * 36 + c4]) = v;
                }
            }
            __syncthreads();

            // preload lane's k-row (32 c) into registers; inner loop stays DS-free
            float wf[32];
            #pragma unroll
            for (int j = 0; j < 8; ++j)
                *reinterpret_cast<float4*>(&wf[j * 4]) =
                    *reinterpret_cast<const float4*>(&wt[t * 36 + j * 4]);

            // w2 accumulation (ascending c, same fma chain as passing prologue)
            #pragma unroll
            for (int c = 0; c < 32; ++c) w2a = fmaf(wf[c], wf[c], w2a);

            const int cg0 = ct * 32;
            #pragma unroll
            for (int cp = 0; cp < 16; ++cp) {
                {   // even c: consume A, prefetch into B
                    const int cnext = (cg0 + cp * 2 + 1) & 255;
                    const float* np = zcol + ((size_t)cnext << 10);
                    Z_ISSUE(zB0, zB1, np);
                    const float wvv = wf[cp * 2];
                    #pragma unroll
                    for (int n = 0; n < 16; ++n) acc[n]      = fmaf(zA0[n], wvv, acc[n]);
                    #pragma unroll
                    for (int n = 0; n < 16; ++n) acc[16 + n] = fmaf(zA1[n], wvv, acc[16 + n]);
                    Z_WAIT(zB0, zB1, acc[0]);
                }
                {   // odd c: consume B, prefetch into A
                    const int cnext = (cg0 + cp * 2 + 2) & 255;
                    const float* np = zcol + ((size_t)cnext << 10);
                    Z_ISSUE(zA0, zA1, np);
                    const float wvv = wf[cp * 2 + 1];
                    #pragma unroll
                    for (int n = 0; n < 16; ++n) acc[n]      = fmaf(zB0[n], wvv, acc[n]);
                    #pragma unroll
                    for (int n = 0; n < 16; ++n) acc[16 + n] = fmaf(zB1[n], wvv, acc[16 + n]);
                    Z_WAIT(zA0, zA1, acc[0]);
                }
            }
        }

        // finalize pass: dist = fl(fl(z2 - 2*dot) + w2); update running (rmin, kt-tag)
        #pragma unroll
        for (int n = 0; n < 32; ++n) {
            const float d = fmaf(-2.0f, acc[n], z2s[n]) + w2a;
            const bool lt = d < rmin[n];
            rmin[n] = lt ? d : rmin[n];
            if (n < 16) {
                const unsigned cand = (tag0 & ~(3u << (2 * n))) | ((unsigned)kt << (2 * n));
                tag0 = lt ? cand : tag0;
            } else {
                const unsigned cand = (tag1 & ~(3u << (2 * (n - 16)))) | ((unsigned)kt << (2 * (n - 16)));
                tag1 = lt ? cand : tag1;
            }
        }
    }

    // ---- exact argmin reduce: u64 = (distbits<<32 | k), min == (min dist, then min k)
    #pragma unroll
    for (int n = 0; n < 32; ++n) {
        const unsigned ktn = ((n < 16 ? tag0 : tag1) >> (2 * (n & 15))) & 3u;
        const unsigned k   = ktn * 256u + (unsigned)t;
        unsigned long long m =
            (((unsigned long long)__float_as_uint(rmin[n])) << 32) | (unsigned long long)k;
        #pragma unroll
        for (int s = 1; s <= 32; s <<= 1) {
            const unsigned long long o = __shfl_xor(m, s, 64);
            m = (o < m) ? o : m;
        }
        if (lane == 0) wred[wv][n] = m;
    }
    __syncthreads();
    if (t < 32) {
        unsigned long long m = wred[0][t];
        #pragma unroll
        for (int q = 1; q < 4; ++q) {
            const unsigned long long o = wred[q][t];
            m = (o < m) ? o : m;
        }
        const int k = (int)(m & 0xFFFFFFFFull);
        idxb[t] = k;
        out[(size_t)2 * OUTHALF + n0 + t] = (float)k;
    }
    __syncthreads();

    // ---- epilogue: gather codes, write code / detached ((c-z)+z chain) coalesced over n
    {
        const int n  = t & 31;
        const int q  = t >> 5;
        const int kn = idxb[n];
        const float* wrow = w + (size_t)kn * 256;
        const size_t obase = (size_t)b * 262144 + hw0;
        #pragma unroll
        for (int cc = 0; cc < 8; ++cc) {
            const int c0 = (q + cc * 8) * 4;
            const float4 cv = *reinterpret_cast<const float4*>(wrow + c0);
            const float cvf[4] = {cv.x, cv.y, cv.z, cv.w};
            #pragma unroll
            for (int u = 0; u < 4; ++u) {
                const size_t off = obase + (size_t)(c0 + u) * 1024 + n;
                const float zz = z[off];
                out[off] = cvf[u];
                out[OUTHALF + off] = (cvf[u] - zz) + zz;
            }
        }
    }
}

extern "C" void kernel_launch(void* const* d_in, const int* in_sizes, int n_in,
                              void* d_out, int out_size, void* d_ws, size_t ws_size,
                              hipStream_t stream) {
    const float* z = (const float*)d_in[0];
    const float* w = (const float*)d_in[1];
    float* out = (float*)d_out;
    vq_kernel<<<1024, 256, 0, stream>>>(z, w, out);
}

// Round 6
// 265.424 us; speedup vs baseline: 2.4230x; 1.5589x over previous
//
#include <hip/hip_runtime.h>

#define OUTHALF 8388608
#define CPAD    320
#define MARGIN  7.5e-4f
#define CAP     24

typedef float f32x4 __attribute__((ext_vector_type(4)));
typedef short bf16x8 __attribute__((ext_vector_type(8)));

__device__ __forceinline__ unsigned short f2bf(float x) {   // RNE fp32 -> bf16
    unsigned u = __float_as_uint(x);
    return (unsigned short)((u + 0x7FFFu + ((u >> 16) & 1u)) >> 16);
}
__device__ __forceinline__ unsigned fkey(float f) {         // order-preserving f32->u32
    unsigned b = __float_as_uint(f);
    return b ^ ((b & 0x80000000u) ? 0xFFFFFFFFu : 0x80000000u);
}
__device__ __forceinline__ float finv(unsigned k) {
    unsigned b = k ^ ((k & 0x80000000u) ? 0x80000000u : 0xFFFFFFFFu);
    return __uint_as_float(b);
}
__device__ __forceinline__ void atomicMinU64(unsigned long long* p, unsigned long long v) {
    unsigned long long cur = *p;
    while (v < cur) {
        unsigned long long old = atomicCAS(p, cur, v);
        if (old == cur) break;
        cur = old;
    }
}

// ---- kernel A1: zplane (bf16 [32768][320], slot256=1.0) + exact z2 ----
__global__ __launch_bounds__(256) void prep_z(const float* __restrict__ z,
                                              float* __restrict__ out) {
    __shared__ float tile[64][65];
    const int t = threadIdx.x;
    const int n0 = blockIdx.x * 64;
    const int b = n0 >> 10, hw0 = n0 & 1023;
    const float* zb = z + (size_t)b * 262144 + hw0;
    unsigned short* zpl = (unsigned short*)out;

    for (int ch = 0; ch < 4; ++ch) {
        __syncthreads();
        #pragma unroll
        for (int r = 0; r < 16; ++r) {
            int c = r * 4 + (t >> 6);
            int nn = t & 63;
            tile[c][nn] = zb[(size_t)(ch * 64 + c) * 1024 + nn];
        }
        __syncthreads();
        #pragma unroll
        for (int i = 0; i < 2; ++i) {
            int id = i * 256 + t;
            int row = id >> 3, seg = id & 7;
            unsigned short tmp[8];
            #pragma unroll
            for (int j = 0; j < 8; ++j) tmp[j] = f2bf(tile[seg * 8 + j][row]);
            *(uint4*)(zpl + (size_t)(n0 + row) * CPAD + ch * 64 + seg * 8) = *(const uint4*)tmp;
        }
    }
    if (t < 64) {
        const float* p = zb + t;
        float s = 0.0f;
        #pragma unroll 8
        for (int c = 0; c < 256; ++c) { float v = p[(size_t)c * 1024]; s = fmaf(v, v, s); }
        ((float*)(out + OUTHALF + 262144))[n0 + t] = s;   // exact z2
        unsigned short* rowp = zpl + (size_t)(n0 + t) * CPAD + 256;
        rowp[0] = 0x3F80;                                  // bf16(1.0)
        for (int j = 1; j < 64; ++j) rowp[j] = 0;
    }
}

// ---- kernel A2: wplane (bf16 [1024][320], slot256=bf16(-w2/2)) + exact w2 ----
__global__ __launch_bounds__(256) void prep_w(const float* __restrict__ w,
                                              float* __restrict__ out) {
    const int k = blockIdx.x * 256 + threadIdx.x;
    if (k >= 1024) return;
    unsigned short* wpl = (unsigned short*)(out + OUTHALF);
    const float4* row = (const float4*)(w + (size_t)k * 256);
    float s = 0.0f;
    #pragma unroll 4
    for (int c4 = 0; c4 < 64; ++c4) {
        float4 v = row[c4];
        s += v.x * v.x;
        s += v.y * v.y;
        s += v.z * v.z;
        s += v.w * v.w;
        unsigned short t4[4] = {f2bf(v.x), f2bf(v.y), f2bf(v.z), f2bf(v.w)};
        *(uint2*)(wpl + (size_t)k * CPAD + c4 * 4) = *(const uint2*)t4;
    }
    ((float*)(out + OUTHALF + 262144 + 32768))[k] = s;     // exact w2
    unsigned short* rowp = wpl + (size_t)k * CPAD + 256;
    rowp[0] = f2bf(-0.5f * s);
    for (int j = 1; j < 64; ++j) rowp[j] = 0;
}

// ---- kernel B: MFMA approx scores + candidate collection + exact recheck ----
__global__ __launch_bounds__(256) void vq_main(const float* __restrict__ z,
                                               const float* __restrict__ w,
                                               float* __restrict__ out) {
    __shared__ uint4 ztb[128 * 9];          // 128 n-rows x 144 B (64c bf16 + pad)
    __shared__ unsigned rmink[128];
    __shared__ unsigned cnt[128];
    __shared__ unsigned candk[128 * CAP];
    __shared__ unsigned long long best[128];
    __shared__ unsigned short ovlist[128];
    __shared__ unsigned ovcnt;

    const int t = threadIdx.x;
    const int lane = t & 63;
    const int wid = t >> 6;
    const int n0 = blockIdx.x * 128;
    const int l15 = lane & 15;
    const int lq  = lane >> 4;

    const unsigned short* zpl = (const unsigned short*)out;
    const unsigned short* wpl = (const unsigned short*)(out + OUTHALF);
    const float* z2arr = (const float*)(out + OUTHALF + 262144);
    const float* w2arr = (const float*)(out + OUTHALF + 262144 + 32768);

    for (int i = t; i < 128; i += 256) {
        rmink[i] = 0xFF7FFFFFu;             // fkey(FLT_MAX)
        cnt[i] = 0;
        best[i] = ~0ull;
    }
    if (t == 0) ovcnt = 0;

    #pragma unroll 1
    for (int pass = 0; pass < 8; ++pass) {
        const int kbase = pass * 128 + wid * 32;
        f32x4 acc[2][8];
        #pragma unroll
        for (int kt = 0; kt < 2; ++kt)
            #pragma unroll
            for (int sub = 0; sub < 8; ++sub) acc[kt][sub] = 0.0f;

        #pragma unroll 1
        for (int chunk = 0; chunk < 5; ++chunk) {
            __syncthreads();
            #pragma unroll
            for (int i = 0; i < 4; ++i) {
                int id = i * 256 + t;
                int row = id >> 3, seg = id & 7;
                ztb[row * 9 + seg] =
                    *(const uint4*)(zpl + (size_t)(n0 + row) * CPAD + chunk * 64 + seg * 8);
            }
            __syncthreads();
            #pragma unroll
            for (int step = 0; step < 2; ++step) {
                const int cs = chunk * 64 + step * 32;
                bf16x8 afr[2];
                #pragma unroll
                for (int kt = 0; kt < 2; ++kt) {
                    int rowk = kbase + kt * 16 + l15;
                    afr[kt] = *(const bf16x8*)(wpl + (size_t)rowk * CPAD + cs + lq * 8);
                }
                #pragma unroll
                for (int sub = 0; sub < 8; ++sub) {
                    int n = sub * 16 + l15;
                    bf16x8 bfr = *(const bf16x8*)((const unsigned short*)ztb + n * 72 + step * 32 + lq * 8);
                    #pragma unroll
                    for (int kt = 0; kt < 2; ++kt)
                        acc[kt][sub] = __builtin_amdgcn_mfma_f32_16x16x32_bf16(
                            afr[kt], bfr, acc[kt][sub], 0, 0, 0);
                }
            }
        }
        // finalize pass (a): settle per-n running min
        #pragma unroll
        for (int sub = 0; sub < 8; ++sub) {
            int n = sub * 16 + l15;
            float m = 3.4e38f;
            #pragma unroll
            for (int kt = 0; kt < 2; ++kt)
                #pragma unroll
                for (int r = 0; r < 4; ++r) m = fminf(m, -2.0f * acc[kt][sub][r]);
            atomicMin(&rmink[n], fkey(m));
        }
        __syncthreads();
        // finalize pass (c): append all k within margin of settled min
        #pragma unroll
        for (int sub = 0; sub < 8; ++sub) {
            int n = sub * 16 + l15;
            float thr = finv(rmink[n]) + MARGIN;
            #pragma unroll
            for (int kt = 0; kt < 2; ++kt)
                #pragma unroll
                for (int r = 0; r < 4; ++r) {
                    float s = -2.0f * acc[kt][sub][r];
                    if (s <= thr) {
                        unsigned slot = atomicAdd(&cnt[n], 1u);
                        if (slot < CAP) candk[n * CAP + slot] = (unsigned)(kbase + kt * 16 + lq * 4 + r);
                    }
                }
        }
        __syncthreads();
    }

    // overflow list
    if (t < 128 && cnt[t] > CAP) {
        unsigned o = atomicAdd(&ovcnt, 1u);
        ovlist[o] = (unsigned short)t;
    }
    // exact recheck of candidates (reference chain: sequential-c fmaf, first-index ties)
    #pragma unroll 1
    for (int p = t; p < 128 * CAP; p += 256) {
        int nl = p / CAP, slot = p % CAP;
        unsigned c_ = cnt[nl];
        if (c_ > CAP || slot >= (int)c_) continue;
        unsigned k = candk[p];
        int n = n0 + nl;
        const float* zc = z + (size_t)(n >> 10) * 262144 + (n & 1023);
        const float* wr = w + (size_t)k * 256;
        float s = 0.0f;
        #pragma unroll 8
        for (int c = 0; c < 256; ++c) s = fmaf(zc[(size_t)c * 1024], wr[c], s);
        float d = fmaf(-2.0f, s, z2arr[n]) + w2arr[k];
        atomicMinU64(&best[nl], ((unsigned long long)__float_as_uint(d) << 32) | k);
    }
    __syncthreads();
    // rare fallback: full exact scan for overflowed n (one wave per n)
    for (unsigned o = wid; o < ovcnt; o += 4) {
        int nl = ovlist[o];
        int n = n0 + nl;
        const float* zc = z + (size_t)(n >> 10) * 262144 + (n & 1023);
        unsigned long long m = ~0ull;
        for (int kk = lane; kk < 1024; kk += 64) {
            const float* wr = w + (size_t)kk * 256;
            float s = 0.0f;
            #pragma unroll 8
            for (int c = 0; c < 256; ++c) s = fmaf(zc[(size_t)c * 1024], wr[c], s);
            float d = fmaf(-2.0f, s, z2arr[n]) + w2arr[kk];
            unsigned long long key = ((unsigned long long)__float_as_uint(d) << 32) | (unsigned)kk;
            m = (key < m) ? key : m;
        }
        #pragma unroll
        for (int sh = 1; sh <= 32; sh <<= 1) {
            unsigned long long o2 = __shfl_xor(m, sh, 64);
            m = (o2 < m) ? o2 : m;
        }
        if (lane == 0) atomicMinU64(&best[nl], m);
    }
    __syncthreads();
    if (t < 128) out[(size_t)2 * OUTHALF + n0 + t] = (float)(unsigned)(best[t] & 0xFFFFFFFFu);
}

// ---- kernel C: gather + write code/detached (round-5 proven epilogue) ----
__global__ __launch_bounds__(256) void epilogue(const float* __restrict__ z,
                                                const float* __restrict__ w,
                                                float* __restrict__ out) {
    const int t = threadIdx.x;
    const int n0 = blockIdx.x * 32;
    const int b = n0 >> 10, hw0 = n0 & 1023;
    const int n = t & 31;
    const int q = t >> 5;
    const int kn = (int)out[(size_t)2 * OUTHALF + n0 + n];
    const float* wrow = w + (size_t)kn * 256;
    const size_t obase = (size_t)b * 262144 + hw0;
    #pragma unroll
    for (int cc = 0; cc < 8; ++cc) {
        const int c0 = (q + cc * 8) * 4;
        const float4 cv = *(const float4*)(wrow + c0);
        const float cvf[4] = {cv.x, cv.y, cv.z, cv.w};
        #pragma unroll
        for (int u = 0; u < 4; ++u) {
            const size_t off = obase + (size_t)(c0 + u) * 1024 + n;
            const float zz = z[off];
            out[off] = cvf[u];
            out[OUTHALF + off] = (cvf[u] - zz) + zz;   // reference rounding chain
        }
    }
}

extern "C" void kernel_launch(void* const* d_in, const int* in_sizes, int n_in,
                              void* d_out, int out_size, void* d_ws, size_t ws_size,
                              hipStream_t stream) {
    const float* z = (const float*)d_in[0];
    const float* w = (const float*)d_in[1];
    float* out = (float*)d_out;
    prep_z  <<<512, 256, 0, stream>>>(z, out);
    prep_w  <<<4,   256, 0, stream>>>(w, out);
    vq_main <<<256, 256, 0, stream>>>(z, w, out);
    epilogue<<<1024, 256, 0, stream>>>(z, w, out);
}